// Round 1
// baseline (1100.398 us; speedup 1.0000x reference)
//
#include <hip/hip_runtime.h>

#define B 2
#define S 2048
#define H 768
#define NH 12
#define HD 64
#define BS (B * S)

// ---------------------------------------------------------------------------
// Tiled fp32 GEMM: out = A[M,768] @ W[768,768] + bias
//   mode 0: scatter epilogue to [B,NH,S,HD]   (QKV projections)
//   mode 1: plain [M,768] row-major           (output projection)
// 64x64 block tile, 256 threads (16x16), 4x4 accum per thread, BK=16.
// ---------------------------------------------------------------------------
__global__ __launch_bounds__(256) void gemm_kernel(
    const float* __restrict__ A, const float* __restrict__ W,
    const float* __restrict__ bias, float* __restrict__ out, int mode)
{
    __shared__ float As[64][17];   // +1 pad breaks bank conflicts
    __shared__ float Bs[16][65];

    const int tid = threadIdx.x;
    const int tx = tid & 15;
    const int ty = tid >> 4;
    const int m0 = blockIdx.x * 64;
    const int n0 = blockIdx.y * 64;

    float acc[4][4] = {};

    for (int k0 = 0; k0 < H; k0 += 16) {
        // A tile 64x16: thread t -> row t/4, cols (t%4)*4 .. +3 (one float4)
        {
            int r = tid >> 2;
            int c = (tid & 3) * 4;
            float4 a = *(const float4*)(A + (size_t)(m0 + r) * H + k0 + c);
            As[r][c + 0] = a.x; As[r][c + 1] = a.y;
            As[r][c + 2] = a.z; As[r][c + 3] = a.w;
        }
        // B tile 16x64: thread t -> row t/16, cols (t%16)*4 .. +3
        {
            int r = tid >> 4;
            int c = (tid & 15) * 4;
            float4 w = *(const float4*)(W + (size_t)(k0 + r) * H + n0 + c);
            Bs[r][c + 0] = w.x; Bs[r][c + 1] = w.y;
            Bs[r][c + 2] = w.z; Bs[r][c + 3] = w.w;
        }
        __syncthreads();
        #pragma unroll
        for (int kk = 0; kk < 16; ++kk) {
            float av[4], bv[4];
            #pragma unroll
            for (int i = 0; i < 4; ++i) av[i] = As[ty * 4 + i][kk];
            #pragma unroll
            for (int j = 0; j < 4; ++j) bv[j] = Bs[kk][tx * 4 + j];
            #pragma unroll
            for (int i = 0; i < 4; ++i)
                #pragma unroll
                for (int j = 0; j < 4; ++j)
                    acc[i][j] = fmaf(av[i], bv[j], acc[i][j]);
        }
        __syncthreads();
    }

    #pragma unroll
    for (int i = 0; i < 4; ++i) {
        int m = m0 + ty * 4 + i;
        int b = m / S, s = m % S;
        #pragma unroll
        for (int j = 0; j < 4; ++j) {
            int n = n0 + tx * 4 + j;
            float v = acc[i][j] + bias[n];
            if (mode == 0) {
                int h = n >> 6, d = n & 63;   // head, dim within head
                out[(((size_t)b * NH + h) * S + s) * HD + d] = v;
            } else {
                out[(size_t)m * H + n] = v;
            }
        }
    }
}

// ---------------------------------------------------------------------------
// RoPE, faithful to the reference quirk: tables are indexed by HEAD index n
// (seq_len_dim=1 on [B,NH,S,HD]), not by sequence position.
//   x2[d] = (d<32) ? -x[2d+1] : x[2(d-32)];  out = x*cos[n,d] + x2*sin[n,d]
// One wave (64 lanes) per (b,n,s) row; partner fetched via __shfl.
// grid.y = 0 -> Q, 1 -> K. In-place.
// ---------------------------------------------------------------------------
__global__ __launch_bounds__(256) void rope_kernel(
    float* __restrict__ Q, float* __restrict__ K,
    const float* __restrict__ cosp, const float* __restrict__ sinp)
{
    int row  = blockIdx.x * 4 + (threadIdx.x >> 6);   // [0, B*NH*S)
    int lane = threadIdx.x & 63;
    float* X = (blockIdx.y == 0) ? Q : K;
    int n = (row / S) % NH;                            // head index
    float x = X[(size_t)row * HD + lane];
    int p = (lane < 32) ? (2 * lane + 1) : (2 * (lane - 32));
    float xp = __shfl(x, p, 64);
    float x2 = (lane < 32) ? -xp : xp;
    float c  = cosp[n * HD + lane];
    float sn = sinp[n * HD + lane];
    X[(size_t)row * HD + lane] = fmaf(x, c, x2 * sn);
}

// ---------------------------------------------------------------------------
// Flash attention, fp32, online softmax. Block per (b*NH, 64-row Q tile).
// LDS tiles padded to 65 floats/row (<=2-way bank conflicts = free).
// ctx written as [B,S,H] so the output GEMM reads it like hidden_states.
// ---------------------------------------------------------------------------
__global__ __launch_bounds__(256) void attn_kernel(
    const float* __restrict__ Q, const float* __restrict__ K,
    const float* __restrict__ V, const float* __restrict__ mask,
    float* __restrict__ ctx)
{
    __shared__ float Qs[64][65];
    __shared__ float Ks[64][65];
    __shared__ float Vs[64][65];
    __shared__ float Ps[64][65];
    __shared__ float mterm[64];

    const int tid = threadIdx.x;
    const int tx = tid & 15;
    const int ty = tid >> 4;
    const int bn = blockIdx.y;          // b*NH + n
    const int b  = bn / NH;
    const int n  = bn % NH;
    const int q0 = blockIdx.x * 64;

    const float* Qb = Q + ((size_t)bn * S + q0) * HD;
    const float* Kb = K + (size_t)bn * S * HD;
    const float* Vb = V + (size_t)bn * S * HD;

    // Load Q tile (64x64): 1024 float4s over 256 threads
    #pragma unroll
    for (int u = 0; u < 4; ++u) {
        int f = tid + u * 256;          // float4 id
        int r = f >> 4, c = (f & 15) * 4;
        float4 qv = *(const float4*)(Qb + r * HD + c);
        Qs[r][c + 0] = qv.x; Qs[r][c + 1] = qv.y;
        Qs[r][c + 2] = qv.z; Qs[r][c + 3] = qv.w;
    }

    float m_i[4], l_i[4], o[4][4];
    #pragma unroll
    for (int i = 0; i < 4; ++i) {
        m_i[i] = -INFINITY; l_i[i] = 0.f;
        #pragma unroll
        for (int j = 0; j < 4; ++j) o[i][j] = 0.f;
    }

    for (int jt = 0; jt < S / 64; ++jt) {
        const float* Kt = Kb + (size_t)jt * 64 * HD;
        const float* Vt = Vb + (size_t)jt * 64 * HD;
        __syncthreads();   // previous iteration done reading Ks/Vs/mterm
        #pragma unroll
        for (int u = 0; u < 4; ++u) {
            int f = tid + u * 256;
            int r = f >> 4, c = (f & 15) * 4;
            float4 kv = *(const float4*)(Kt + r * HD + c);
            Ks[r][c + 0] = kv.x; Ks[r][c + 1] = kv.y;
            Ks[r][c + 2] = kv.z; Ks[r][c + 3] = kv.w;
            float4 vv = *(const float4*)(Vt + r * HD + c);
            Vs[r][c + 0] = vv.x; Vs[r][c + 1] = vv.y;
            Vs[r][c + 2] = vv.z; Vs[r][c + 3] = vv.w;
        }
        if (tid < 64)
            mterm[tid] = (1.0f - mask[b * S + jt * 64 + tid]) * (-10000.0f);
        __syncthreads();

        // S tile: sc[i][j] = q_row(4ty+i) . k_row(4tx+j)
        float sc[4][4] = {};
        #pragma unroll 8
        for (int kk = 0; kk < 64; ++kk) {
            float av[4], bv[4];
            #pragma unroll
            for (int i = 0; i < 4; ++i) av[i] = Qs[ty * 4 + i][kk];
            #pragma unroll
            for (int j = 0; j < 4; ++j) bv[j] = Ks[tx * 4 + j][kk];
            #pragma unroll
            for (int i = 0; i < 4; ++i)
                #pragma unroll
                for (int j = 0; j < 4; ++j)
                    sc[i][j] = fmaf(av[i], bv[j], sc[i][j]);
        }
        #pragma unroll
        for (int i = 0; i < 4; ++i)
            #pragma unroll
            for (int j = 0; j < 4; ++j)
                sc[i][j] = fmaf(sc[i][j], 0.125f, mterm[tx * 4 + j]);

        // online softmax update (rows live on 16 consecutive lanes: width-16 shuffles)
        #pragma unroll
        for (int i = 0; i < 4; ++i) {
            float rmax = fmaxf(fmaxf(sc[i][0], sc[i][1]), fmaxf(sc[i][2], sc[i][3]));
            #pragma unroll
            for (int off = 8; off >= 1; off >>= 1)
                rmax = fmaxf(rmax, __shfl_xor(rmax, off, 16));
            float m_new = fmaxf(m_i[i], rmax);
            float alpha = expf(m_i[i] - m_new);
            float rsum = 0.f;
            #pragma unroll
            for (int j = 0; j < 4; ++j) {
                float p = expf(sc[i][j] - m_new);
                sc[i][j] = p;
                rsum += p;
            }
            #pragma unroll
            for (int off = 8; off >= 1; off >>= 1)
                rsum += __shfl_xor(rsum, off, 16);
            l_i[i] = alpha * l_i[i] + rsum;
            m_i[i] = m_new;
            #pragma unroll
            for (int j = 0; j < 4; ++j) {
                o[i][j] *= alpha;
                Ps[ty * 4 + i][tx * 4 + j] = sc[i][j];
            }
        }
        __syncthreads();

        // PV: o[i][j] += sum_kk P[4ty+i][kk] * V[kk][4tx+j]
        #pragma unroll 8
        for (int kk = 0; kk < 64; ++kk) {
            float pa[4], vb[4];
            #pragma unroll
            for (int i = 0; i < 4; ++i) pa[i] = Ps[ty * 4 + i][kk];
            #pragma unroll
            for (int j = 0; j < 4; ++j) vb[j] = Vs[kk][tx * 4 + j];
            #pragma unroll
            for (int i = 0; i < 4; ++i)
                #pragma unroll
                for (int j = 0; j < 4; ++j)
                    o[i][j] = fmaf(pa[i], vb[j], o[i][j]);
        }
    }

    // epilogue: ctx[b, s, n*64+d] = o / l
    #pragma unroll
    for (int i = 0; i < 4; ++i) {
        float inv = 1.0f / l_i[i];
        int s = q0 + ty * 4 + i;
        #pragma unroll
        for (int j = 0; j < 4; ++j) {
            int d = tx * 4 + j;
            ctx[((size_t)b * S + s) * H + n * HD + d] = o[i][j] * inv;
        }
    }
}

// ---------------------------------------------------------------------------
extern "C" void kernel_launch(void* const* d_in, const int* in_sizes, int n_in,
                              void* d_out, int out_size, void* d_ws, size_t ws_size,
                              hipStream_t stream)
{
    const float* hs   = (const float*)d_in[0];
    const float* mask = (const float*)d_in[1];
    const float* Wq   = (const float*)d_in[2];
    const float* bq   = (const float*)d_in[3];
    const float* Wk   = (const float*)d_in[4];
    const float* bk   = (const float*)d_in[5];
    const float* Wv   = (const float*)d_in[6];
    const float* bv   = (const float*)d_in[7];
    const float* Wo   = (const float*)d_in[8];
    const float* bo   = (const float*)d_in[9];
    const float* cosp = (const float*)d_in[10];
    const float* sinp = (const float*)d_in[11];
    float* out = (float*)d_out;

    const size_t per = (size_t)B * NH * S * HD;   // 3,145,728 floats each
    float* Q  = (float*)d_ws;
    float* K  = Q + per;
    float* V  = K + per;
    float* CT = V + per;                           // ctx as [B,S,H]

    dim3 gemm_grid(BS / 64, H / 64);
    gemm_kernel<<<gemm_grid, 256, 0, stream>>>(hs, Wq, bq, Q, 0);
    gemm_kernel<<<gemm_grid, 256, 0, stream>>>(hs, Wk, bk, K, 0);
    gemm_kernel<<<gemm_grid, 256, 0, stream>>>(hs, Wv, bv, V, 0);

    rope_kernel<<<dim3(B * NH * S / 4, 2), 256, 0, stream>>>(Q, K, cosp, sinp);

    attn_kernel<<<dim3(S / 64, B * NH), 256, 0, stream>>>(Q, K, V, mask, CT);

    gemm_kernel<<<gemm_grid, 256, 0, stream>>>(CT, Wo, bo, out, 1);
}

// Round 2
// 585.921 us; speedup vs baseline: 1.8781x; 1.8781x over previous
//
#include <hip/hip_runtime.h>

#define B 2
#define S 2048
#define H 768
#define NH 12
#define HD 64
#define BS (B * S)

typedef unsigned short u16;
typedef short short8 __attribute__((ext_vector_type(8)));
typedef float f32x4 __attribute__((ext_vector_type(4)));

// fp32 -> bf16, round-to-nearest-even (values are finite; no NaN path needed)
__device__ __forceinline__ u16 f2bf(float f) {
    union { float f; unsigned u; } c; c.f = f;
    unsigned u = c.u + 0x7FFFu + ((c.u >> 16) & 1u);
    return (u16)(u >> 16);
}

// ---------------------------------------------------------------------------
// Tiled fp32 GEMM: out = A[M,768] @ W[768,768] + bias
//   mode 0: fp32 scatter to [B,NH,S,HD]      (Q,K projections)
//   mode 1: fp32 plain [M,768] row-major     (output projection)
//   mode 2: bf16 scatter to [B,NH,S,HD]      (V projection)
// ---------------------------------------------------------------------------
__global__ __launch_bounds__(256) void gemm_kernel(
    const float* __restrict__ A, const float* __restrict__ W,
    const float* __restrict__ bias, void* __restrict__ out, int mode)
{
    __shared__ float As[64][17];
    __shared__ float Bs[16][65];

    const int tid = threadIdx.x;
    const int tx = tid & 15;
    const int ty = tid >> 4;
    const int m0 = blockIdx.x * 64;
    const int n0 = blockIdx.y * 64;

    float acc[4][4] = {};

    for (int k0 = 0; k0 < H; k0 += 16) {
        {
            int r = tid >> 2;
            int c = (tid & 3) * 4;
            float4 a = *(const float4*)(A + (size_t)(m0 + r) * H + k0 + c);
            As[r][c + 0] = a.x; As[r][c + 1] = a.y;
            As[r][c + 2] = a.z; As[r][c + 3] = a.w;
        }
        {
            int r = tid >> 4;
            int c = (tid & 15) * 4;
            float4 w = *(const float4*)(W + (size_t)(k0 + r) * H + n0 + c);
            Bs[r][c + 0] = w.x; Bs[r][c + 1] = w.y;
            Bs[r][c + 2] = w.z; Bs[r][c + 3] = w.w;
        }
        __syncthreads();
        #pragma unroll
        for (int kk = 0; kk < 16; ++kk) {
            float av[4], bv[4];
            #pragma unroll
            for (int i = 0; i < 4; ++i) av[i] = As[ty * 4 + i][kk];
            #pragma unroll
            for (int j = 0; j < 4; ++j) bv[j] = Bs[kk][tx * 4 + j];
            #pragma unroll
            for (int i = 0; i < 4; ++i)
                #pragma unroll
                for (int j = 0; j < 4; ++j)
                    acc[i][j] = fmaf(av[i], bv[j], acc[i][j]);
        }
        __syncthreads();
    }

    const int h = n0 >> 6;   // head index (tile never straddles a head)
    #pragma unroll
    for (int i = 0; i < 4; ++i) {
        int m = m0 + ty * 4 + i;
        int b = m / S, s = m % S;
        if (mode == 0) {
            float* o = (float*)out;
            #pragma unroll
            for (int j = 0; j < 4; ++j) {
                int d = tx * 4 + j;
                o[(((size_t)b * NH + h) * S + s) * HD + d] =
                    acc[i][j] + bias[n0 + d];
            }
        } else if (mode == 1) {
            float* o = (float*)out;
            #pragma unroll
            for (int j = 0; j < 4; ++j) {
                int n = n0 + tx * 4 + j;
                o[(size_t)m * H + n] = acc[i][j] + bias[n];
            }
        } else {
            u16* o = (u16*)out;
            ushort4 pk;
            pk.x = f2bf(acc[i][0] + bias[n0 + tx * 4 + 0]);
            pk.y = f2bf(acc[i][1] + bias[n0 + tx * 4 + 1]);
            pk.z = f2bf(acc[i][2] + bias[n0 + tx * 4 + 2]);
            pk.w = f2bf(acc[i][3] + bias[n0 + tx * 4 + 3]);
            *(ushort4*)(o + (((size_t)b * NH + h) * S + s) * HD + tx * 4) = pk;
        }
    }
}

// ---------------------------------------------------------------------------
// RoPE (faithful to reference: tables indexed by HEAD index) + bf16 cast.
// grid.y==0: Q (scaled by 1/sqrt(HD), folded into scores), grid.y==1: K.
// ---------------------------------------------------------------------------
__global__ __launch_bounds__(256) void rope_kernel(
    const float* __restrict__ Qf, const float* __restrict__ Kf,
    u16* __restrict__ Qb, u16* __restrict__ Kb,
    const float* __restrict__ cosp, const float* __restrict__ sinp)
{
    int row  = blockIdx.x * 4 + (threadIdx.x >> 6);   // [0, B*NH*S)
    int lane = threadIdx.x & 63;
    const float* src = (blockIdx.y == 0) ? Qf : Kf;
    u16*         dst = (blockIdx.y == 0) ? Qb : Kb;
    const float scale = (blockIdx.y == 0) ? 0.125f : 1.0f;
    int n = (row / S) % NH;                            // head index
    float x = src[(size_t)row * HD + lane];
    int p = (lane < 32) ? (2 * lane + 1) : (2 * (lane - 32));
    float xp = __shfl(x, p, 64);
    float x2 = (lane < 32) ? -xp : xp;
    float c  = cosp[n * HD + lane];
    float sn = sinp[n * HD + lane];
    dst[(size_t)row * HD + lane] = f2bf(fmaf(x, c, x2 * sn) * scale);
}

// ---------------------------------------------------------------------------
// Transpose V [B,NH,S,HD] bf16 -> VT [B,NH,HD,S] bf16, 64x64 tiles via LDS.
// ---------------------------------------------------------------------------
__global__ __launch_bounds__(256) void vtrans_kernel(
    const u16* __restrict__ V, u16* __restrict__ VT)
{
    __shared__ u16 Lt[64 * 68];   // stride 68: 8*68 dwords != 0 mod 32
    const int tid = threadIdx.x;
    const int bn = blockIdx.y;
    const int s0 = blockIdx.x * 64;
    const u16* Vb = V + ((size_t)bn * S + s0) * HD;

    #pragma unroll
    for (int u = 0; u < 2; ++u) {
        int f = tid + u * 256;
        int r = f >> 3, c8 = (f & 7) * 8;
        short8 v = *(const short8*)(Vb + (size_t)r * HD + c8);
        #pragma unroll
        for (int j = 0; j < 8; ++j) Lt[r * 68 + c8 + j] = (u16)v[j];
    }
    __syncthreads();
    #pragma unroll
    for (int u = 0; u < 2; ++u) {
        int f = tid + u * 256;
        int d = f >> 3, k8 = (f & 7) * 8;
        short8 t;
        #pragma unroll
        for (int j = 0; j < 8; ++j) t[j] = (short)Lt[(k8 + j) * 68 + d];
        *(short8*)(VT + ((size_t)bn * HD + d) * S + s0 + k8) = t;
    }
}

// ---------------------------------------------------------------------------
// Flash attention, bf16 MFMA (16x16x32), fp32 online softmax.
// Block = (64-row Q tile, one (b,head)); 4 waves, wave w owns rows 16w..16w+15.
// Frag layouts (m89/m91/m93-verified): A/B lane&15 = non-K idx, quad*8+j = K;
// C/D: col = lane&15, row = quad*4 + reg.
// ---------------------------------------------------------------------------
__global__ __launch_bounds__(256) void attn_mfma_kernel(
    const u16* __restrict__ Q, const u16* __restrict__ K,
    const u16* __restrict__ VT, const float* __restrict__ mask,
    float* __restrict__ ctx)
{
    __shared__ alignas(16) u16 Ks[64 * 72];     // [key][dim], stride 72
    __shared__ alignas(16) u16 VsT[64 * 72];    // [dim][key], stride 72
    __shared__ alignas(16) u16 Ps[4 * 16 * 72]; // per-wave [qrow][key]
    __shared__ float mterm[64];

    const int tid  = threadIdx.x;
    const int w    = tid >> 6;
    const int lane = tid & 63;
    const int quad = lane >> 4;
    const int l15  = lane & 15;
    const int bn = blockIdx.y, b = bn / NH, hh = bn % NH;
    const int q0 = blockIdx.x * 64;

    // Q A-fragments straight from global (16B aligned, rows contiguous)
    const u16* Qp = Q + ((size_t)bn * S + q0 + w * 16 + l15) * HD + quad * 8;
    const short8 qa0 = *(const short8*)(Qp);
    const short8 qa1 = *(const short8*)(Qp + 32);

    const u16* Kb = K + (size_t)bn * S * HD;
    const u16* Vb = VT + (size_t)bn * HD * S;

    f32x4 o[4];
    float m_i[4], l_i[4];
    #pragma unroll
    for (int n = 0; n < 4; ++n) o[n] = (f32x4){0.f, 0.f, 0.f, 0.f};
    #pragma unroll
    for (int r = 0; r < 4; ++r) { m_i[r] = -INFINITY; l_i[r] = 0.f; }

    for (int jt = 0; jt < S / 64; ++jt) {
        __syncthreads();   // prior iteration done reading Ks/VsT/mterm
        #pragma unroll
        for (int u = 0; u < 2; ++u) {
            int f = tid + u * 256;
            int r = f >> 3, c8 = (f & 7) * 8;
            *(short8*)&Ks[r * 72 + c8] =
                *(const short8*)(Kb + (size_t)(jt * 64 + r) * HD + c8);
            *(short8*)&VsT[r * 72 + c8] =
                *(const short8*)(Vb + (size_t)r * S + jt * 64 + c8);
        }
        if (tid < 64)
            mterm[tid] = (1.0f - mask[b * S + jt * 64 + tid]) * (-10000.0f);
        __syncthreads();

        // S strip: 4 n-tiles of 16 cols, K-dim 64 in two chunks of 32
        f32x4 sc[4];
        #pragma unroll
        for (int n = 0; n < 4; ++n) {
            const u16* kr = &Ks[(n * 16 + l15) * 72 + quad * 8];
            const short8 kb0 = *(const short8*)(kr);
            const short8 kb1 = *(const short8*)(kr + 32);
            f32x4 acc = (f32x4){0.f, 0.f, 0.f, 0.f};
            acc = __builtin_amdgcn_mfma_f32_16x16x32_bf16(qa0, kb0, acc, 0, 0, 0);
            acc = __builtin_amdgcn_mfma_f32_16x16x32_bf16(qa1, kb1, acc, 0, 0, 0);
            const float mt = mterm[n * 16 + l15];
            #pragma unroll
            for (int r = 0; r < 4; ++r) acc[r] += mt;
            sc[n] = acc;
        }

        // online softmax: rows quad*4+r live on the 16 lanes of this quad
        #pragma unroll
        for (int r = 0; r < 4; ++r) {
            float rm = fmaxf(fmaxf(sc[0][r], sc[1][r]), fmaxf(sc[2][r], sc[3][r]));
            #pragma unroll
            for (int off = 8; off >= 1; off >>= 1)
                rm = fmaxf(rm, __shfl_xor(rm, off, 16));
            float mn = fmaxf(m_i[r], rm);
            float al = __expf(m_i[r] - mn);
            m_i[r] = mn;
            float rs = 0.f;
            #pragma unroll
            for (int n = 0; n < 4; ++n) {
                float p = __expf(sc[n][r] - mn);
                sc[n][r] = p;
                rs += p;
            }
            #pragma unroll
            for (int off = 8; off >= 1; off >>= 1)
                rs += __shfl_xor(rs, off, 16);
            l_i[r] = al * l_i[r] + rs;
            #pragma unroll
            for (int n = 0; n < 4; ++n) {
                o[n][r] *= al;
                Ps[w * 1152 + (quad * 4 + r) * 72 + n * 16 + l15] = f2bf(sc[n][r]);
            }
        }

        // P is per-wave private: lgkmcnt(0) orders the cross-lane LDS RAW
        asm volatile("s_waitcnt lgkmcnt(0)" ::: "memory");

        const u16* Pw = &Ps[w * 1152 + l15 * 72 + quad * 8];
        const short8 pa0 = *(const short8*)(Pw);
        const short8 pa1 = *(const short8*)(Pw + 32);
        #pragma unroll
        for (int n = 0; n < 4; ++n) {
            const u16* vr = &VsT[(n * 16 + l15) * 72 + quad * 8];
            const short8 vb0 = *(const short8*)(vr);
            const short8 vb1 = *(const short8*)(vr + 32);
            o[n] = __builtin_amdgcn_mfma_f32_16x16x32_bf16(pa0, vb0, o[n], 0, 0, 0);
            o[n] = __builtin_amdgcn_mfma_f32_16x16x32_bf16(pa1, vb1, o[n], 0, 0, 0);
        }
    }

    // epilogue: ctx[b, s, head*64 + d] = o / l
    #pragma unroll
    for (int r = 0; r < 4; ++r) {
        float inv = 1.0f / l_i[r];
        int s = q0 + w * 16 + quad * 4 + r;
        #pragma unroll
        for (int n = 0; n < 4; ++n)
            ctx[((size_t)b * S + s) * H + hh * 64 + n * 16 + l15] = o[n][r] * inv;
    }
}

// ---------------------------------------------------------------------------
extern "C" void kernel_launch(void* const* d_in, const int* in_sizes, int n_in,
                              void* d_out, int out_size, void* d_ws, size_t ws_size,
                              hipStream_t stream)
{
    const float* hs   = (const float*)d_in[0];
    const float* mask = (const float*)d_in[1];
    const float* Wq   = (const float*)d_in[2];
    const float* bq   = (const float*)d_in[3];
    const float* Wk   = (const float*)d_in[4];
    const float* bk   = (const float*)d_in[5];
    const float* Wv   = (const float*)d_in[6];
    const float* bv   = (const float*)d_in[7];
    const float* Wo   = (const float*)d_in[8];
    const float* bo   = (const float*)d_in[9];
    const float* cosp = (const float*)d_in[10];
    const float* sinp = (const float*)d_in[11];
    float* out = (float*)d_out;

    const size_t per = (size_t)B * NH * S * HD;   // 3,145,728 elements
    float* Qf = (float*)d_ws;                     // fp32 Q   [ 0,12) MB
    float* Kf = Qf + per;                         // fp32 K   [12,24) MB
    u16*   Vb = (u16*)(Kf + per);                 // bf16 V   [24,30) MB
    u16*   Qb = Vb + per;                         // bf16 Q   [30,36) MB
    u16*   Kb = Qb + per;                         // bf16 K   [36,42) MB
    u16*   VT = Kb + per;                         // bf16 V^T [42,48) MB
    float* CT = Qf;                               // ctx aliases dead Qf

    dim3 gemm_grid(BS / 64, H / 64);
    gemm_kernel<<<gemm_grid, 256, 0, stream>>>(hs, Wq, bq, Qf, 0);
    gemm_kernel<<<gemm_grid, 256, 0, stream>>>(hs, Wk, bk, Kf, 0);
    gemm_kernel<<<gemm_grid, 256, 0, stream>>>(hs, Wv, bv, Vb, 2);

    rope_kernel<<<dim3(B * NH * S / 4, 2), 256, 0, stream>>>(
        Qf, Kf, Qb, Kb, cosp, sinp);

    vtrans_kernel<<<dim3(S / 64, B * NH), 256, 0, stream>>>(Vb, VT);

    attn_mfma_kernel<<<dim3(S / 64, B * NH), 256, 0, stream>>>(
        Qb, Kb, VT, mask, CT);

    gemm_kernel<<<gemm_grid, 256, 0, stream>>>(CT, Wo, bo, out, 1);
}

// Round 3
// 247.383 us; speedup vs baseline: 4.4482x; 2.3685x over previous
//
#include <hip/hip_runtime.h>

#define B 2
#define S 2048
#define H 768
#define NH 12
#define HD 64
#define BS (B * S)

typedef unsigned short u16;
typedef short short8 __attribute__((ext_vector_type(8)));
typedef float f32x4 __attribute__((ext_vector_type(4)));

// fp32 -> bf16 round-to-nearest-even
__device__ __forceinline__ u16 f2bf(float f) {
    union { float f; unsigned u; } c; c.f = f;
    unsigned u = c.u + 0x7FFFu + ((c.u >> 16) & 1u);
    return (u16)(u >> 16);
}
__device__ __forceinline__ float bf2f(u16 h) {
    union { unsigned u; float f; } c; c.u = ((unsigned)h) << 16;
    return c.f;
}

// ---------------------------------------------------------------------------
// Prep 1: hidden_states fp32 -> bf16 (8 elements/thread)
// ---------------------------------------------------------------------------
__global__ __launch_bounds__(256) void prep_hs_kernel(
    const float* __restrict__ src, u16* __restrict__ dst)
{
    size_t i = ((size_t)blockIdx.x * 256 + threadIdx.x) * 8;
    float4 a = *(const float4*)(src + i);
    float4 b = *(const float4*)(src + i + 4);
    short8 p;
    p[0] = (short)f2bf(a.x); p[1] = (short)f2bf(a.y);
    p[2] = (short)f2bf(a.z); p[3] = (short)f2bf(a.w);
    p[4] = (short)f2bf(b.x); p[5] = (short)f2bf(b.y);
    p[6] = (short)f2bf(b.z); p[7] = (short)f2bf(b.w);
    *(short8*)(dst + i) = p;
}

// ---------------------------------------------------------------------------
// Prep 2: W [768,768] fp32 row-major -> WT [768,768] bf16 (WT[n][k] = W[k][n])
// blockIdx.z selects weight: 0,1,2 -> Wq,Wk,Wv stacked in WTqkv; 3 -> WTo.
// ---------------------------------------------------------------------------
__global__ __launch_bounds__(256) void prep_w_kernel(
    const float* __restrict__ Wq, const float* __restrict__ Wk,
    const float* __restrict__ Wv, const float* __restrict__ Wo,
    u16* __restrict__ WTqkv, u16* __restrict__ WTo)
{
    __shared__ float Lt[64 * 65];
    const int t = threadIdx.x;
    const int z = blockIdx.z;
    const float* W = (z == 0) ? Wq : (z == 1) ? Wk : (z == 2) ? Wv : Wo;
    u16* D = (z == 3) ? WTo : (WTqkv + (size_t)z * H * H);
    const int k0 = blockIdx.x * 64, n0 = blockIdx.y * 64;

    #pragma unroll
    for (int u = 0; u < 4; ++u) {
        int f = t + u * 256;
        int r = f >> 4, c4 = (f & 15) * 4;
        float4 w = *(const float4*)(W + (size_t)(k0 + r) * H + n0 + c4);
        Lt[r * 65 + c4 + 0] = w.x; Lt[r * 65 + c4 + 1] = w.y;
        Lt[r * 65 + c4 + 2] = w.z; Lt[r * 65 + c4 + 3] = w.w;
    }
    __syncthreads();
    #pragma unroll
    for (int u = 0; u < 4; ++u) {
        int f = t + u * 256;
        int n = f >> 4, k4 = (f & 15) * 4;
        ushort4 p;
        p.x = f2bf(Lt[(k4 + 0) * 65 + n]);
        p.y = f2bf(Lt[(k4 + 1) * 65 + n]);
        p.z = f2bf(Lt[(k4 + 2) * 65 + n]);
        p.w = f2bf(Lt[(k4 + 3) * 65 + n]);
        *(ushort4*)(D + (size_t)(n0 + n) * H + k0 + k4) = p;
    }
}

// ---------------------------------------------------------------------------
// Fused QKV GEMM, bf16 MFMA 16x16x32. C[4096, 2304] = hsb @ WTqkv^T.
// 128x128 tile, 4 waves (2x2 of 64x64), BK=64, LDS stride 72 (2-way = free).
// Epilogue: cols 0..767 -> Qb, 768..1535 -> Kb (bf16 [B,NH,S,HD], +bias),
//           1536..2303 -> VT (bf16 [B,NH,HD,S], +bias, ushort4 stores).
// ---------------------------------------------------------------------------
__global__ __launch_bounds__(256) void gemm_qkv_kernel(
    const u16* __restrict__ A, const u16* __restrict__ BT,
    const float* __restrict__ bq, const float* __restrict__ bk,
    const float* __restrict__ bv,
    u16* __restrict__ Qb, u16* __restrict__ Kb, u16* __restrict__ VT)
{
    __shared__ alignas(16) u16 As[128 * 72];
    __shared__ alignas(16) u16 Bs[128 * 72];

    const int tid  = threadIdx.x;
    const int w    = tid >> 6;
    const int lane = tid & 63;
    const int quad = lane >> 4;
    const int l15  = lane & 15;
    const int wm = (w & 1) * 64, wn = (w >> 1) * 64;
    const int m0 = blockIdx.x * 128;
    const int n0 = blockIdx.y * 128;

    f32x4 acc[4][4];
    #pragma unroll
    for (int i = 0; i < 4; ++i)
        #pragma unroll
        for (int j = 0; j < 4; ++j) acc[i][j] = (f32x4){0.f, 0.f, 0.f, 0.f};

    for (int k0 = 0; k0 < H; k0 += 64) {
        __syncthreads();
        #pragma unroll
        for (int u = 0; u < 4; ++u) {
            int f = tid + u * 256;
            int r = f >> 3, c8 = (f & 7) * 8;
            *(short8*)&As[r * 72 + c8] =
                *(const short8*)(A + (size_t)(m0 + r) * H + k0 + c8);
            *(short8*)&Bs[r * 72 + c8] =
                *(const short8*)(BT + (size_t)(n0 + r) * H + k0 + c8);
        }
        __syncthreads();
        #pragma unroll
        for (int kc = 0; kc < 64; kc += 32) {
            short8 af[4], bf[4];
            #pragma unroll
            for (int mi = 0; mi < 4; ++mi)
                af[mi] = *(const short8*)&As[(wm + mi * 16 + l15) * 72 + kc + quad * 8];
            #pragma unroll
            for (int ni = 0; ni < 4; ++ni)
                bf[ni] = *(const short8*)&Bs[(wn + ni * 16 + l15) * 72 + kc + quad * 8];
            #pragma unroll
            for (int mi = 0; mi < 4; ++mi)
                #pragma unroll
                for (int ni = 0; ni < 4; ++ni)
                    acc[mi][ni] = __builtin_amdgcn_mfma_f32_16x16x32_bf16(
                        af[mi], bf[ni], acc[mi][ni], 0, 0, 0);
        }
    }

    #pragma unroll
    for (int mi = 0; mi < 4; ++mi) {
        const int mbase = m0 + wm + mi * 16 + quad * 4;   // rows mbase..mbase+3
        #pragma unroll
        for (int ni = 0; ni < 4; ++ni) {
            const int col = n0 + wn + ni * 16 + l15;      // 0..2303
            const int which = col / H;                    // frag-uniform
            const int c = col - which * H;
            const int h = c >> 6, d = c & 63;
            if (which == 2) {
                const float bias = bv[c];
                const int b_ = mbase >> 11, s = mbase & (S - 1);
                ushort4 pk;
                pk.x = f2bf(acc[mi][ni][0] + bias);
                pk.y = f2bf(acc[mi][ni][1] + bias);
                pk.z = f2bf(acc[mi][ni][2] + bias);
                pk.w = f2bf(acc[mi][ni][3] + bias);
                *(ushort4*)&VT[(((size_t)b_ * NH + h) * HD + d) * S + s] = pk;
            } else {
                u16* dst = (which == 0) ? Qb : Kb;
                const float bias = (which == 0) ? bq[c] : bk[c];
                #pragma unroll
                for (int r = 0; r < 4; ++r) {
                    int m = mbase + r;
                    int b_ = m >> 11, s = m & (S - 1);
                    dst[(((size_t)b_ * NH + h) * S + s) * HD + d] =
                        f2bf(acc[mi][ni][r] + bias);
                }
            }
        }
    }
}

// ---------------------------------------------------------------------------
// Output projection: out[4096,768] fp32 = ctxb @ WTo^T + bo
// ---------------------------------------------------------------------------
__global__ __launch_bounds__(256) void gemm_out_kernel(
    const u16* __restrict__ A, const u16* __restrict__ BT,
    const float* __restrict__ bo, float* __restrict__ out)
{
    __shared__ alignas(16) u16 As[128 * 72];
    __shared__ alignas(16) u16 Bs[128 * 72];

    const int tid  = threadIdx.x;
    const int w    = tid >> 6;
    const int lane = tid & 63;
    const int quad = lane >> 4;
    const int l15  = lane & 15;
    const int wm = (w & 1) * 64, wn = (w >> 1) * 64;
    const int m0 = blockIdx.x * 128;
    const int n0 = blockIdx.y * 128;

    f32x4 acc[4][4];
    #pragma unroll
    for (int i = 0; i < 4; ++i)
        #pragma unroll
        for (int j = 0; j < 4; ++j) acc[i][j] = (f32x4){0.f, 0.f, 0.f, 0.f};

    for (int k0 = 0; k0 < H; k0 += 64) {
        __syncthreads();
        #pragma unroll
        for (int u = 0; u < 4; ++u) {
            int f = tid + u * 256;
            int r = f >> 3, c8 = (f & 7) * 8;
            *(short8*)&As[r * 72 + c8] =
                *(const short8*)(A + (size_t)(m0 + r) * H + k0 + c8);
            *(short8*)&Bs[r * 72 + c8] =
                *(const short8*)(BT + (size_t)(n0 + r) * H + k0 + c8);
        }
        __syncthreads();
        #pragma unroll
        for (int kc = 0; kc < 64; kc += 32) {
            short8 af[4], bf[4];
            #pragma unroll
            for (int mi = 0; mi < 4; ++mi)
                af[mi] = *(const short8*)&As[(wm + mi * 16 + l15) * 72 + kc + quad * 8];
            #pragma unroll
            for (int ni = 0; ni < 4; ++ni)
                bf[ni] = *(const short8*)&Bs[(wn + ni * 16 + l15) * 72 + kc + quad * 8];
            #pragma unroll
            for (int mi = 0; mi < 4; ++mi)
                #pragma unroll
                for (int ni = 0; ni < 4; ++ni)
                    acc[mi][ni] = __builtin_amdgcn_mfma_f32_16x16x32_bf16(
                        af[mi], bf[ni], acc[mi][ni], 0, 0, 0);
        }
    }

    #pragma unroll
    for (int mi = 0; mi < 4; ++mi) {
        const int mbase = m0 + wm + mi * 16 + quad * 4;
        #pragma unroll
        for (int ni = 0; ni < 4; ++ni) {
            const int col = n0 + wn + ni * 16 + l15;
            const float bias = bo[col];
            #pragma unroll
            for (int r = 0; r < 4; ++r)
                out[(size_t)(mbase + r) * H + col] = acc[mi][ni][r] + bias;
        }
    }
}

// ---------------------------------------------------------------------------
// RoPE (reference quirk: tables indexed by HEAD), bf16 in-place.
// grid.y==0: Q (also folds 1/sqrt(HD)), grid.y==1: K.
// ---------------------------------------------------------------------------
__global__ __launch_bounds__(256) void rope_kernel(
    u16* __restrict__ Qb, u16* __restrict__ Kb,
    const float* __restrict__ cosp, const float* __restrict__ sinp)
{
    int row  = blockIdx.x * 4 + (threadIdx.x >> 6);   // [0, B*NH*S)
    int lane = threadIdx.x & 63;
    u16* X = (blockIdx.y == 0) ? Qb : Kb;
    const float scale = (blockIdx.y == 0) ? 0.125f : 1.0f;
    int n = (row / S) % NH;                            // head index
    float x = bf2f(X[(size_t)row * HD + lane]);
    int p = (lane < 32) ? (2 * lane + 1) : (2 * (lane - 32));
    float xp = __shfl(x, p, 64);
    float x2 = (lane < 32) ? -xp : xp;
    float c  = cosp[n * HD + lane];
    float sn = sinp[n * HD + lane];
    X[(size_t)row * HD + lane] = f2bf(fmaf(x, c, x2 * sn) * scale);
}

// ---------------------------------------------------------------------------
// Flash attention, bf16 MFMA (16x16x32), fp32 online softmax. ctx out bf16.
// ---------------------------------------------------------------------------
__global__ __launch_bounds__(256) void attn_mfma_kernel(
    const u16* __restrict__ Q, const u16* __restrict__ K,
    const u16* __restrict__ VT, const float* __restrict__ mask,
    u16* __restrict__ ctx)
{
    __shared__ alignas(16) u16 Ks[64 * 72];     // [key][dim]
    __shared__ alignas(16) u16 VsT[64 * 72];    // [dim][key]
    __shared__ alignas(16) u16 Ps[4 * 16 * 72]; // per-wave [qrow][key]
    __shared__ float mterm[64];

    const int tid  = threadIdx.x;
    const int w    = tid >> 6;
    const int lane = tid & 63;
    const int quad = lane >> 4;
    const int l15  = lane & 15;
    const int bn = blockIdx.y, b = bn / NH, hh = bn % NH;
    const int q0 = blockIdx.x * 64;

    const u16* Qp = Q + ((size_t)bn * S + q0 + w * 16 + l15) * HD + quad * 8;
    const short8 qa0 = *(const short8*)(Qp);
    const short8 qa1 = *(const short8*)(Qp + 32);

    const u16* Kb = K + (size_t)bn * S * HD;
    const u16* Vb = VT + (size_t)bn * HD * S;

    f32x4 o[4];
    float m_i[4], l_i[4];
    #pragma unroll
    for (int n = 0; n < 4; ++n) o[n] = (f32x4){0.f, 0.f, 0.f, 0.f};
    #pragma unroll
    for (int r = 0; r < 4; ++r) { m_i[r] = -INFINITY; l_i[r] = 0.f; }

    for (int jt = 0; jt < S / 64; ++jt) {
        __syncthreads();
        #pragma unroll
        for (int u = 0; u < 2; ++u) {
            int f = tid + u * 256;
            int r = f >> 3, c8 = (f & 7) * 8;
            *(short8*)&Ks[r * 72 + c8] =
                *(const short8*)(Kb + (size_t)(jt * 64 + r) * HD + c8);
            *(short8*)&VsT[r * 72 + c8] =
                *(const short8*)(Vb + (size_t)r * S + jt * 64 + c8);
        }
        if (tid < 64)
            mterm[tid] = (1.0f - mask[b * S + jt * 64 + tid]) * (-10000.0f);
        __syncthreads();

        f32x4 sc[4];
        #pragma unroll
        for (int n = 0; n < 4; ++n) {
            const u16* kr = &Ks[(n * 16 + l15) * 72 + quad * 8];
            const short8 kb0 = *(const short8*)(kr);
            const short8 kb1 = *(const short8*)(kr + 32);
            f32x4 a = (f32x4){0.f, 0.f, 0.f, 0.f};
            a = __builtin_amdgcn_mfma_f32_16x16x32_bf16(qa0, kb0, a, 0, 0, 0);
            a = __builtin_amdgcn_mfma_f32_16x16x32_bf16(qa1, kb1, a, 0, 0, 0);
            const float mt = mterm[n * 16 + l15];
            #pragma unroll
            for (int r = 0; r < 4; ++r) a[r] += mt;
            sc[n] = a;
        }

        #pragma unroll
        for (int r = 0; r < 4; ++r) {
            float rm = fmaxf(fmaxf(sc[0][r], sc[1][r]), fmaxf(sc[2][r], sc[3][r]));
            #pragma unroll
            for (int off = 8; off >= 1; off >>= 1)
                rm = fmaxf(rm, __shfl_xor(rm, off, 16));
            float mn = fmaxf(m_i[r], rm);
            float al = __expf(m_i[r] - mn);
            m_i[r] = mn;
            float rs = 0.f;
            #pragma unroll
            for (int n = 0; n < 4; ++n) {
                float p = __expf(sc[n][r] - mn);
                sc[n][r] = p;
                rs += p;
            }
            #pragma unroll
            for (int off = 8; off >= 1; off >>= 1)
                rs += __shfl_xor(rs, off, 16);
            l_i[r] = al * l_i[r] + rs;
            #pragma unroll
            for (int n = 0; n < 4; ++n) {
                o[n][r] *= al;
                Ps[w * 1152 + (quad * 4 + r) * 72 + n * 16 + l15] = f2bf(sc[n][r]);
            }
        }

        asm volatile("s_waitcnt lgkmcnt(0)" ::: "memory");

        const u16* Pw = &Ps[w * 1152 + l15 * 72 + quad * 8];
        const short8 pa0 = *(const short8*)(Pw);
        const short8 pa1 = *(const short8*)(Pw + 32);
        #pragma unroll
        for (int n = 0; n < 4; ++n) {
            const u16* vr = &VsT[(n * 16 + l15) * 72 + quad * 8];
            const short8 vb0 = *(const short8*)(vr);
            const short8 vb1 = *(const short8*)(vr + 32);
            o[n] = __builtin_amdgcn_mfma_f32_16x16x32_bf16(pa0, vb0, o[n], 0, 0, 0);
            o[n] = __builtin_amdgcn_mfma_f32_16x16x32_bf16(pa1, vb1, o[n], 0, 0, 0);
        }
    }

    #pragma unroll
    for (int r = 0; r < 4; ++r) {
        float inv = 1.0f / l_i[r];
        int s = q0 + w * 16 + quad * 4 + r;
        #pragma unroll
        for (int n = 0; n < 4; ++n)
            ctx[((size_t)b * S + s) * H + hh * 64 + n * 16 + l15] =
                f2bf(o[n][r] * inv);
    }
}

// ---------------------------------------------------------------------------
extern "C" void kernel_launch(void* const* d_in, const int* in_sizes, int n_in,
                              void* d_out, int out_size, void* d_ws, size_t ws_size,
                              hipStream_t stream)
{
    const float* hs   = (const float*)d_in[0];
    const float* mask = (const float*)d_in[1];
    const float* Wq   = (const float*)d_in[2];
    const float* bq   = (const float*)d_in[3];
    const float* Wk   = (const float*)d_in[4];
    const float* bk   = (const float*)d_in[5];
    const float* Wv   = (const float*)d_in[6];
    const float* bv   = (const float*)d_in[7];
    const float* Wo   = (const float*)d_in[8];
    const float* bo   = (const float*)d_in[9];
    const float* cosp = (const float*)d_in[10];
    const float* sinp = (const float*)d_in[11];
    float* out = (float*)d_out;

    const size_t per = (size_t)B * NH * S * HD;   // 3,145,728
    u16* ws    = (u16*)d_ws;
    u16* hsb   = ws;                              // bf16 hidden  [BS,H]
    u16* WTqkv = hsb + per;                       // bf16 [2304,768]
    u16* WTo   = WTqkv + (size_t)3 * H * H;       // bf16 [768,768]
    u16* Qb    = WTo + (size_t)H * H;             // bf16 [B,NH,S,HD]
    u16* Kb    = Qb + per;
    u16* VT    = Kb + per;                        // bf16 [B,NH,HD,S]
    u16* ctxb  = VT + per;                        // bf16 [BS,H]

    prep_hs_kernel<<<(BS * H) / 2048, 256, 0, stream>>>(hs, hsb);
    prep_w_kernel<<<dim3(12, 12, 4), 256, 0, stream>>>(
        Wq, Wk, Wv, Wo, WTqkv, WTo);

    gemm_qkv_kernel<<<dim3(BS / 128, 2304 / 128), 256, 0, stream>>>(
        hsb, WTqkv, bq, bk, bv, Qb, Kb, VT);

    rope_kernel<<<dim3(B * NH * S / 4, 2), 256, 0, stream>>>(
        Qb, Kb, cosp, sinp);

    attn_mfma_kernel<<<dim3(S / 64, B * NH), 256, 0, stream>>>(
        Qb, Kb, VT, mask, ctxb);

    gemm_out_kernel<<<dim3(BS / 128, H / 128), 256, 0, stream>>>(
        ctxb, WTo, bo, out);
}